// Round 2
// baseline (52.804 us; speedup 1.0000x reference)
//
#include <hip/hip_runtime.h>
#include <hip/hip_bf16.h>
#include <stdint.h>

// MultiDense: out[b,s,:] = values[b,s,:] @ W[lookups[b]] + bias[lookups[b]]
// B=16384, S=4, IN=OUT=128, 64 experts.
//
// R2: latency-bound fix. Grid 64 experts x 16 chunks = 1024 blocks (4/CU).
// Per block: scan 1024 lookups -> uint16 list; stage W[e]^T bf16 swizzled in
// LDS (rotated b64 writes to kill write-bank conflicts); 4 waves each take
// dynamic groups of 4 samples (16 GEMM rows), mfma_f32_16x16x32_bf16 over
// 128 output cols. e = blockIdx&63 pins each expert's 16 blocks to one XCD
// for W L2 reuse.

#define NDIMS   64
#define IN_DIM  128
#define OUT_DIM 128
#define BATCH   16384
#define SEQ     4
#define NC      16
#define CHUNK   (BATCH / NC)       // 1024
#define THREADS 256
#define NWAVE   4
#define GRP     4                  // samples per wave-group (16 rows)

using bf16x8 = __attribute__((ext_vector_type(8))) __bf16;
using f32x4  = __attribute__((ext_vector_type(4))) float;

static __device__ inline uint16_t bf16bits(float f) {
    __bf16 h = (__bf16)f;                   // RNE convert
    return __builtin_bit_cast(uint16_t, h);
}

static __device__ inline bf16x8 cvt8(f32x4 v0, f32x4 v1) {
    bf16x8 r;
    r[0] = (__bf16)v0[0]; r[1] = (__bf16)v0[1];
    r[2] = (__bf16)v0[2]; r[3] = (__bf16)v0[3];
    r[4] = (__bf16)v1[0]; r[5] = (__bf16)v1[1];
    r[6] = (__bf16)v1[2]; r[7] = (__bf16)v1[3];
    return r;
}

__global__ __launch_bounds__(THREADS, 4)
void multidense_kernel(const float* __restrict__ values,
                       const float* __restrict__ W,
                       const float* __restrict__ bias,
                       const int*   __restrict__ lookups,
                       float*       __restrict__ out)
{
    // w_lds byte (n*256 + x) holds Wt[n][(x ^ ((n&7)<<4)) / 2]  (bf16 pairs)
    __shared__ __align__(16) unsigned char w_lds[OUT_DIM * IN_DIM * 2];  // 32 KiB
    __shared__ unsigned short list[CHUNK];                               // 2 KiB
    __shared__ int nm_sh;

    const int tid = threadIdx.x;
    const int e   = blockIdx.x & 63;        // all 16 chunks of expert e -> same XCD
    const int c   = blockIdx.x >> 6;        // chunk 0..15

    if (tid == 0) nm_sh = 0;
    __syncthreads();

    // ---- Stage W[e]^T -> LDS bf16, transposed + swizzled ----
    // thread: o = tid&127 (coalesced global reads over o), quads of i.
    // Per-lane rotation of the i-quad sequence spreads same-(o&7) lanes
    // across banks on the ds_write_b64s.
    {
        const float* We = W + (size_t)e * (IN_DIM * OUT_DIM);
        const int o   = tid & 127;
        const int ih  = tid >> 7;            // 0..1
        const int rot = (o >> 3) & 15;
        const int swz = (o & 7) << 4;
        unsigned char* wrow = &w_lds[o * 256];
        #pragma unroll 4
        for (int qq = 0; qq < 16; ++qq) {
            int q  = ih * 16 + ((qq + rot) & 15);   // quad 0..31
            int i0 = q * 4;
            float f0 = We[(i0 + 0) * OUT_DIM + o];
            float f1 = We[(i0 + 1) * OUT_DIM + o];
            float f2 = We[(i0 + 2) * OUT_DIM + o];
            float f3 = We[(i0 + 3) * OUT_DIM + o];
            uint32_t lo = (uint32_t)bf16bits(f0) | ((uint32_t)bf16bits(f1) << 16);
            uint32_t hi = (uint32_t)bf16bits(f2) | ((uint32_t)bf16bits(f3) << 16);
            uint64_t pk = (uint64_t)lo | ((uint64_t)hi << 32);
            *(uint64_t*)(wrow + ((i0 * 2) ^ swz)) = pk;
        }
    }

    // ---- Scan this chunk of lookups for expert e ----
    {
        const int cbase = c * CHUNK;
        #pragma unroll
        for (int t = 0; t < CHUNK / THREADS; ++t) {
            int idx = cbase + t * THREADS + tid;
            if (lookups[idx] == e) {
                int p = atomicAdd(&nm_sh, 1);
                list[p] = (unsigned short)idx;
            }
        }
    }
    __syncthreads();

    const int nm = nm_sh;
    if (nm == 0) return;

    const int lane = tid & 63;
    const int wid  = tid >> 6;
    const int l15  = lane & 15;
    const int l4   = lane >> 4;              // 0..3
    const int swzB = (l15 & 7) << 4;         // B-fragment row swizzle

    // bias per lane, one per n-fragment
    float bias_c[8];
    #pragma unroll
    for (int nf = 0; nf < 8; ++nf) bias_c[nf] = bias[e * OUT_DIM + nf * 16 + l15];

    // ---- Main loop: each wave takes groups of 4 samples (16 GEMM rows) ----
    for (int grp = wid; grp * GRP < nm; grp += NWAVE) {
        const int sbase = grp * GRP;

        // A row pointer: fragment layout row = l15, k = ks*32 + l4*8 + j
        int pos  = sbase + (l15 >> 2);
        int posc = pos < nm ? pos : nm - 1;          // clamp tail (stores masked)
        int b    = (int)list[posc];
        const float* pA = values + (size_t)(b * SEQ + (l15 & 3)) * IN_DIM + l4 * 8;

        f32x4 acc[8];
        #pragma unroll
        for (int nf = 0; nf < 8; ++nf) {
            f32x4 a;
            a[0] = bias_c[nf]; a[1] = bias_c[nf]; a[2] = bias_c[nf]; a[3] = bias_c[nf];
            acc[nf] = a;
        }

        #pragma unroll
        for (int ks = 0; ks < 4; ++ks) {
            f32x4 v0 = *(const f32x4*)(pA + ks * 32);
            f32x4 v1 = *(const f32x4*)(pA + ks * 32 + 4);
            bf16x8 afr = cvt8(v0, v1);
            const int koff = (ks * 64 + l4 * 16) ^ swzB;
            #pragma unroll
            for (int nf = 0; nf < 8; ++nf) {
                const bf16x8 bfr = *(const bf16x8*)(&w_lds[(nf * 16 + l15) * 256 + koff]);
                acc[nf] = __builtin_amdgcn_mfma_f32_16x16x32_bf16(afr, bfr, acc[nf], 0, 0, 0);
            }
        }

        // ---- Store: D layout col = l15, row = l4*4 + r ----
        #pragma unroll
        for (int r = 0; r < 4; ++r) {
            int row  = l4 * 4 + r;
            int pos2 = sbase + (row >> 2);
            if (pos2 < nm) {
                int b2 = (int)list[pos2];
                float* po = out + (size_t)(b2 * SEQ + (row & 3)) * OUT_DIM + l15;
                #pragma unroll
                for (int nf = 0; nf < 8; ++nf) po[nf * 16] = acc[nf][r];
            }
        }
    }
}

extern "C" void kernel_launch(void* const* d_in, const int* in_sizes, int n_in,
                              void* d_out, int out_size, void* d_ws, size_t ws_size,
                              hipStream_t stream) {
    const float* values  = (const float*)d_in[0];
    const float* W       = (const float*)d_in[1];
    const float* bias    = (const float*)d_in[2];
    const int*   lookups = (const int*)d_in[3];
    float* out = (float*)d_out;

    hipLaunchKernelGGL(multidense_kernel, dim3(NDIMS * NC), dim3(THREADS), 0, stream,
                       values, W, bias, lookups, out);
}